// Round 5
// baseline (486.873 us; speedup 1.0000x reference)
//
#include <hip/hip_runtime.h>
#include <math.h>

#define H 128
#define IN 2048
#define PROJ 64
#define BT 32768      // B*T rows of x
#define T_STEPS 512
#define BATCH 64
#define BM 128
#define BKA 64

using f32x4  = __attribute__((ext_vector_type(4))) float;
using bfrag  = __attribute__((ext_vector_type(8))) short;   // 8 bf16
using h2_t   = __attribute__((ext_vector_type(2))) _Float16;

// v_cvt_pk_bf16_f32: d.lo = bf16(lo), d.hi = bf16(hi)  (RNE)
__device__ __forceinline__ unsigned cvtpk(float lo, float hi) {
  unsigned r;
  asm("v_cvt_pk_bf16_f32 %0, %1, %2" : "=v"(r) : "v"(lo), "v"(hi));
  return r;
}

// ---------------------------------------------------------------------------
// Kernel A: xp1[BT][H] = x[BT][IN] @ W_ih1^T + (b_ih1+b_hh1), bf16 MFMA.
// 256 blocks x 512 thr (8 waves, 2Mx4N). Tile 128(M) x 128(N=H) x 64(K).
// Reg-staged 1-deep pipeline, one barrier per chunk, XOR-swizzled LDS.
// ~60 us, near the 268 MB / 6.3 TB/s HBM floor. UNCHANGED from R4.
// ---------------------------------------------------------------------------
__global__ __launch_bounds__(512) void xp1_gemm(
    const float* __restrict__ x, const float* __restrict__ W,
    const float* __restrict__ b1, const float* __restrict__ b2,
    float* __restrict__ xp1) {
  __shared__ __align__(16) char As[2][BM * BKA * 2];   // 2 x 16 KB
  __shared__ __align__(16) char Bs[2][H * BKA * 2];    // 2 x 16 KB
  const int t  = threadIdx.x;
  const int m0 = blockIdx.x * BM;
  const int wv = t >> 6, l = t & 63;
  const int wm = wv >> 2;
  const int wn = wv & 3;
  const int lr = l & 15;
  const int lq = l >> 4;

  const float* xg[4];
  const float* wg[4];
  int so[4];
#pragma unroll
  for (int i = 0; i < 4; ++i) {
    int c = t + 512 * i, r = c >> 4, k4 = c & 15;
    xg[i] = x + (size_t)(m0 + r) * IN + k4 * 4;
    wg[i] = W + (size_t)r * IN + k4 * 4;
    so[i] = (r * 128 + k4 * 8) ^ ((r & 7) << 4);
  }
  int ao[2][4], bo[2][2];
#pragma unroll
  for (int kf = 0; kf < 2; ++kf) {
#pragma unroll
    for (int mf = 0; mf < 4; ++mf) {
      int r = wm * 64 + mf * 16 + lr;
      ao[kf][mf] = (r * 128 + kf * 64 + lq * 16) ^ ((r & 7) << 4);
    }
#pragma unroll
    for (int nf = 0; nf < 2; ++nf) {
      int r = wn * 32 + nf * 16 + lr;
      bo[kf][nf] = (r * 128 + kf * 64 + lq * 16) ^ ((r & 7) << 4);
    }
  }

  f32x4 acc[4][2];
#pragma unroll
  for (int mf = 0; mf < 4; ++mf)
#pragma unroll
    for (int nf = 0; nf < 2; ++nf)
#pragma unroll
      for (int j = 0; j < 4; ++j) acc[mf][nf][j] = 0.f;

  float4 xr[4], wr[4];
#pragma unroll
  for (int i = 0; i < 4; ++i) {
    xr[i] = *(const float4*)&xg[i][0];
    wr[i] = *(const float4*)&wg[i][0];
  }
#pragma unroll
  for (int i = 0; i < 4; ++i) {
    uint2 ux; ux.x = cvtpk(xr[i].x, xr[i].y); ux.y = cvtpk(xr[i].z, xr[i].w);
    *(uint2*)(As[0] + so[i]) = ux;
    uint2 uw; uw.x = cvtpk(wr[i].x, wr[i].y); uw.y = cvtpk(wr[i].z, wr[i].w);
    *(uint2*)(Bs[0] + so[i]) = uw;
  }
  __syncthreads();

  for (int tc = 0; tc < 32; ++tc) {
    const int kc = (tc + 1) * BKA;
    if (tc < 31) {
#pragma unroll
      for (int i = 0; i < 4; ++i) {
        xr[i] = *(const float4*)&xg[i][kc];
        wr[i] = *(const float4*)&wg[i][kc];
      }
    }
    const char* Ab = As[tc & 1];
    const char* Bb = Bs[tc & 1];
#pragma unroll
    for (int kf = 0; kf < 2; ++kf) {
      bfrag af[4], bf[2];
#pragma unroll
      for (int mf = 0; mf < 4; ++mf) af[mf] = *(const bfrag*)(Ab + ao[kf][mf]);
#pragma unroll
      for (int nf = 0; nf < 2; ++nf) bf[nf] = *(const bfrag*)(Bb + bo[kf][nf]);
#pragma unroll
      for (int mf = 0; mf < 4; ++mf)
#pragma unroll
        for (int nf = 0; nf < 2; ++nf)
          acc[mf][nf] = __builtin_amdgcn_mfma_f32_16x16x32_bf16(
              af[mf], bf[nf], acc[mf][nf], 0, 0, 0);
    }
    if (tc < 31) {
      char* Aw = As[(tc + 1) & 1];
      char* Bw = Bs[(tc + 1) & 1];
#pragma unroll
      for (int i = 0; i < 4; ++i) {
        uint2 ux; ux.x = cvtpk(xr[i].x, xr[i].y); ux.y = cvtpk(xr[i].z, xr[i].w);
        *(uint2*)(Aw + so[i]) = ux;
        uint2 uw; uw.x = cvtpk(wr[i].x, wr[i].y); uw.y = cvtpk(wr[i].z, wr[i].w);
        *(uint2*)(Bw + so[i]) = uw;
      }
    }
    __syncthreads();
  }

  // epilogue: C/D layout col = lane&15, row = (lane>>4)*4 + j   [m89]
#pragma unroll
  for (int nf = 0; nf < 2; ++nf) {
    int n = wn * 32 + nf * 16 + lr;
    float bias = b1[n] + b2[n];
#pragma unroll
    for (int mf = 0; mf < 4; ++mf) {
      int mr = m0 + wm * 64 + mf * 16 + lq * 4;
#pragma unroll
      for (int j = 0; j < 4; ++j)
        xp1[(size_t)(mr + j) * H + n] = acc[mf][nf][j] + bias;
    }
  }
}

// ---------------------------------------------------------------------------
// Kernel B: fused 2-layer tanh RNN + projection + LayerNorm, f16 dot2 path.
// amdgpu_waves_per_eu(1,2): exactly one 512-thr block/CU runs (64 blocks on
// 256 CUs) -> stop the scheduler from targeting 8 waves/EU and remat'ing the
// weight loads inside the loop (R3/R4 showed VGPR=52 < 48 weight regs).
// In-loop PIN makes remat strictly unprofitable: weights must occupy VGPRs
// at every iteration.
// ---------------------------------------------------------------------------
struct Wrow { unsigned p0, p1, p2, p3, p4, p5, p6, p7; };  // 16 f16 = 8 h2

__device__ __forceinline__ unsigned pkh(float x, float y) {
  h2_t p = {(_Float16)x, (_Float16)y};
  return __builtin_bit_cast(unsigned, p);
}

__device__ __forceinline__ float d2(unsigned w, int h, float acc) {
  return __builtin_amdgcn_fdot2(__builtin_bit_cast(h2_t, w),
                                __builtin_bit_cast(h2_t, (unsigned)h), acc,
                                false);
}

__device__ __forceinline__ float dot16(Wrow w, int4 lo, int4 hi, float acc) {
  acc = d2(w.p0, lo.x, acc);
  acc = d2(w.p1, lo.y, acc);
  acc = d2(w.p2, lo.z, acc);
  acc = d2(w.p3, lo.w, acc);
  acc = d2(w.p4, hi.x, acc);
  acc = d2(w.p5, hi.y, acc);
  acc = d2(w.p6, hi.z, acc);
  acc = d2(w.p7, hi.w, acc);
  return acc;
}

__device__ __forceinline__ Wrow loadrow(const float* p) {
  float4 a = *(const float4*)p;
  float4 b = *(const float4*)(p + 4);
  float4 c = *(const float4*)(p + 8);
  float4 d = *(const float4*)(p + 12);
  Wrow w = {pkh(a.x, a.y), pkh(a.z, a.w), pkh(b.x, b.y), pkh(b.z, b.w),
            pkh(c.x, c.y), pkh(c.z, c.w), pkh(d.x, d.y), pkh(d.z, d.w)};
  return w;
}

#define PIN(W)                                                              \
  asm volatile("" : "+v"(W.p0), "+v"(W.p1), "+v"(W.p2), "+v"(W.p3),         \
                    "+v"(W.p4), "+v"(W.p5), "+v"(W.p6), "+v"(W.p7))

template <int CTRL>
__device__ __forceinline__ float dpp_add(float x) {
  return x + __builtin_bit_cast(
                 float, __builtin_amdgcn_mov_dpp(__builtin_bit_cast(int, x),
                                                 CTRL, 0xf, 0xf, true));
}

__device__ __forceinline__ float red8(float v) {
  v = dpp_add<0xB1>(v);    // quad_perm [1,0,3,2]  (+ lane^1)
  v = dpp_add<0x4E>(v);    // quad_perm [2,3,0,1]  (+ lane^2)
  v = dpp_add<0x141>(v);   // row_half_mirror      (+ other quad of 8-group)
  return v;
}

__device__ __forceinline__ float fast_tanh(float x) {
  float e = __expf(2.0f * x);
  return 1.0f - 2.0f / (e + 1.0f);
}

__global__ __launch_bounds__(512)
__attribute__((amdgpu_waves_per_eu(1, 2)))
void rnn_fused(
    const float* __restrict__ xp1,
    const float* __restrict__ W_hh1, const float* __restrict__ W_ih2,
    const float* __restrict__ W_hh2, const float* __restrict__ b_ih2,
    const float* __restrict__ b_hh2, const float* __restrict__ W_proj,
    const float* __restrict__ b_proj, const float* __restrict__ gamma,
    const float* __restrict__ beta, float* __restrict__ out) {
  __shared__ __align__(16) _Float16 h1s[2][H];
  __shared__ __align__(16) _Float16 h2s[2][H];
  const int t = threadIdx.x;
  const int b = blockIdx.x;
  const int l = t & 63;
  const int w = t >> 6;
  const int g = (l >> 3) & 7;
  const int q = l & 7;
  const int r0 = 16 * w + g;
  const int r1 = r0 + 8;

  Wrow W1r0 = loadrow(&W_hh1[r0 * H + 16 * q]);
  Wrow W1r1 = loadrow(&W_hh1[r1 * H + 16 * q]);
  Wrow W2r0 = loadrow(&W_ih2[r0 * H + 16 * q]);
  Wrow W2r1 = loadrow(&W_ih2[r1 * H + 16 * q]);
  Wrow W3r0 = loadrow(&W_hh2[r0 * H + 16 * q]);
  Wrow W3r1 = loadrow(&W_hh2[r1 * H + 16 * q]);
  PIN(W1r0); PIN(W1r1); PIN(W2r0); PIN(W2r1); PIN(W3r0); PIN(W3r1);

  const float bias2_0 = b_ih2[r0] + b_hh2[r0];
  const float bias2_1 = b_ih2[r1] + b_hh2[r1];

  if (t < H) { h1s[0][t] = (_Float16)0.f; h2s[0][t] = (_Float16)0.f; }
  __syncthreads();

  const float* xpr0 = xp1 + (size_t)b * T_STEPS * H + r0;
  const float* xpr1 = xpr0 + 8;
  float xpA0 = xpr0[0];
  float xpA1 = xpr1[0];

  for (int ts = 0; ts < T_STEPS; ++ts) {
    // re-pin every iteration: weights must live in VGPRs here -> remat of the
    // global loads inside the loop is strictly unprofitable for the allocator
    PIN(W1r0); PIN(W1r1); PIN(W2r0); PIN(W2r1); PIN(W3r0); PIN(W3r1);

    const int cur = ts & 1;
    const _Float16* h1p = h1s[cur];
    const _Float16* h2p = h2s[cur];
    _Float16* h1w = h1s[cur ^ 1];
    _Float16* h2w = h2s[cur ^ 1];

    float nx0 = 0.f, nx1 = 0.f;
    if (ts + 1 < T_STEPS) {              // prefetch next step's xp values
      nx0 = xpr0[(size_t)(ts + 1) * H];
      nx1 = xpr1[(size_t)(ts + 1) * H];
    }

    // phase A: W_hh1 . h1_old  and  W_hh2 . h2_old
    int4 l1 = *(const int4*)&h1p[16 * q];
    int4 u1 = *(const int4*)&h1p[16 * q + 8];
    int4 l2 = *(const int4*)&h2p[16 * q];
    int4 u2 = *(const int4*)&h2p[16 * q + 8];
    float a0 = dot16(W1r0, l1, u1, 0.f);
    float a1 = dot16(W1r1, l1, u1, 0.f);
    float c0 = dot16(W3r0, l2, u2, 0.f);
    float c1 = dot16(W3r1, l2, u2, 0.f);
    a0 = red8(a0); a1 = red8(a1);
    c0 = red8(c0); c1 = red8(c1);
    float h1n0 = fast_tanh(xpA0 + a0);
    float h1n1 = fast_tanh(xpA1 + a1);
    if (q == 0) { h1w[r0] = (_Float16)h1n0; h1w[r1] = (_Float16)h1n1; }
    __syncthreads();  // (1) h1_new visible; reads of old buffers done

    // phase B: W_ih2 . h1_new
    int4 nl = *(const int4*)&h1w[16 * q];
    int4 nu = *(const int4*)&h1w[16 * q + 8];
    float bb0 = dot16(W2r0, nl, nu, 0.f);
    float bb1 = dot16(W2r1, nl, nu, 0.f);
    bb0 = red8(bb0); bb1 = red8(bb1);
    float h2n0 = fast_tanh(bias2_0 + bb0 + c0);
    float h2n1 = fast_tanh(bias2_1 + bb1 + c1);
    if (q == 0) { h2w[r0] = (_Float16)h2n0; h2w[r1] = (_Float16)h2n1; }
    __syncthreads();  // (2) h2_new visible for next step
    xpA0 = nx0; xpA1 = nx1;
  }
  // T_STEPS even -> final h2 lives in h2s[0]

  // projection + LayerNorm; lanes 0..63 == wave 0 exactly
  if (t < PROJ) {
    const float* wp = W_proj + t * H;
    float z = b_proj[t];
#pragma unroll
    for (int i = 0; i < 32; ++i) {
      float4 wv = *(const float4*)&wp[4 * i];
      z = fmaf(wv.x, (float)h2s[0][4 * i + 0], z);
      z = fmaf(wv.y, (float)h2s[0][4 * i + 1], z);
      z = fmaf(wv.z, (float)h2s[0][4 * i + 2], z);
      z = fmaf(wv.w, (float)h2s[0][4 * i + 3], z);
    }
    float s = z;
#pragma unroll
    for (int d = 1; d < 64; d <<= 1) s += __shfl_xor(s, d);
    float mu = s * 0.015625f;
    float dz = z - mu;
    float v = dz * dz;
#pragma unroll
    for (int d = 1; d < 64; d <<= 1) v += __shfl_xor(v, d);
    float rstd = rsqrtf(v * 0.015625f + 1e-5f);
    out[b * PROJ + t] = dz * rstd * gamma[t] + beta[t];
  }
}

extern "C" void kernel_launch(void* const* d_in, const int* in_sizes, int n_in,
                              void* d_out, int out_size, void* d_ws, size_t ws_size,
                              hipStream_t stream) {
  const float* x      = (const float*)d_in[0];
  const float* W_ih1  = (const float*)d_in[1];
  const float* W_hh1  = (const float*)d_in[2];
  const float* b_ih1  = (const float*)d_in[3];
  const float* b_hh1  = (const float*)d_in[4];
  const float* W_ih2  = (const float*)d_in[5];
  const float* W_hh2  = (const float*)d_in[6];
  const float* b_ih2  = (const float*)d_in[7];
  const float* b_hh2  = (const float*)d_in[8];
  const float* W_proj = (const float*)d_in[9];
  const float* b_proj = (const float*)d_in[10];
  const float* gamma  = (const float*)d_in[11];
  const float* beta   = (const float*)d_in[12];

  float* xp1 = (float*)d_ws;   // BT*H*4 = 16 MB scratch

  xp1_gemm<<<BT / BM, 512, 0, stream>>>(x, W_ih1, b_ih1, b_hh1, xp1);
  rnn_fused<<<BATCH, 512, 0, stream>>>(xp1, W_hh1, W_ih2, W_hh2, b_ih2, b_hh2,
                                       W_proj, b_proj, gamma, beta,
                                       (float*)d_out);
}

// Round 6
// 430.787 us; speedup vs baseline: 1.1302x; 1.1302x over previous
//
#include <hip/hip_runtime.h>
#include <math.h>

#define H 128
#define IN 2048
#define PROJ 64
#define BT 32768      // B*T rows of x
#define T_STEPS 512
#define BATCH 64
#define BM 128
#define BKA 64

using f32x4  = __attribute__((ext_vector_type(4))) float;
using bfrag  = __attribute__((ext_vector_type(8))) short;   // 8 bf16
using h2_t   = __attribute__((ext_vector_type(2))) _Float16;

// v_cvt_pk_bf16_f32: d.lo = bf16(lo), d.hi = bf16(hi)  (RNE)
__device__ __forceinline__ unsigned cvtpk(float lo, float hi) {
  unsigned r;
  asm("v_cvt_pk_bf16_f32 %0, %1, %2" : "=v"(r) : "v"(lo), "v"(hi));
  return r;
}

// ---------------------------------------------------------------------------
// Kernel A: xp1[BT][H] = x[BT][IN] @ W_ih1^T + (b_ih1+b_hh1), bf16 MFMA.
// 256 blocks x 512 thr (8 waves, 2Mx4N). Tile 128(M) x 128(N=H) x 64(K).
// Reg-staged 1-deep pipeline, one barrier per chunk, XOR-swizzled LDS.
// ~60 us, near the 268 MB / 6.3 TB/s HBM floor. UNCHANGED from R4.
// ---------------------------------------------------------------------------
__global__ __launch_bounds__(512) void xp1_gemm(
    const float* __restrict__ x, const float* __restrict__ W,
    const float* __restrict__ b1, const float* __restrict__ b2,
    float* __restrict__ xp1) {
  __shared__ __align__(16) char As[2][BM * BKA * 2];   // 2 x 16 KB
  __shared__ __align__(16) char Bs[2][H * BKA * 2];    // 2 x 16 KB
  const int t  = threadIdx.x;
  const int m0 = blockIdx.x * BM;
  const int wv = t >> 6, l = t & 63;
  const int wm = wv >> 2;
  const int wn = wv & 3;
  const int lr = l & 15;
  const int lq = l >> 4;

  const float* xg[4];
  const float* wg[4];
  int so[4];
#pragma unroll
  for (int i = 0; i < 4; ++i) {
    int c = t + 512 * i, r = c >> 4, k4 = c & 15;
    xg[i] = x + (size_t)(m0 + r) * IN + k4 * 4;
    wg[i] = W + (size_t)r * IN + k4 * 4;
    so[i] = (r * 128 + k4 * 8) ^ ((r & 7) << 4);
  }
  int ao[2][4], bo[2][2];
#pragma unroll
  for (int kf = 0; kf < 2; ++kf) {
#pragma unroll
    for (int mf = 0; mf < 4; ++mf) {
      int r = wm * 64 + mf * 16 + lr;
      ao[kf][mf] = (r * 128 + kf * 64 + lq * 16) ^ ((r & 7) << 4);
    }
#pragma unroll
    for (int nf = 0; nf < 2; ++nf) {
      int r = wn * 32 + nf * 16 + lr;
      bo[kf][nf] = (r * 128 + kf * 64 + lq * 16) ^ ((r & 7) << 4);
    }
  }

  f32x4 acc[4][2];
#pragma unroll
  for (int mf = 0; mf < 4; ++mf)
#pragma unroll
    for (int nf = 0; nf < 2; ++nf)
#pragma unroll
      for (int j = 0; j < 4; ++j) acc[mf][nf][j] = 0.f;

  float4 xr[4], wr[4];
#pragma unroll
  for (int i = 0; i < 4; ++i) {
    xr[i] = *(const float4*)&xg[i][0];
    wr[i] = *(const float4*)&wg[i][0];
  }
#pragma unroll
  for (int i = 0; i < 4; ++i) {
    uint2 ux; ux.x = cvtpk(xr[i].x, xr[i].y); ux.y = cvtpk(xr[i].z, xr[i].w);
    *(uint2*)(As[0] + so[i]) = ux;
    uint2 uw; uw.x = cvtpk(wr[i].x, wr[i].y); uw.y = cvtpk(wr[i].z, wr[i].w);
    *(uint2*)(Bs[0] + so[i]) = uw;
  }
  __syncthreads();

  for (int tc = 0; tc < 32; ++tc) {
    const int kc = (tc + 1) * BKA;
    if (tc < 31) {
#pragma unroll
      for (int i = 0; i < 4; ++i) {
        xr[i] = *(const float4*)&xg[i][kc];
        wr[i] = *(const float4*)&wg[i][kc];
      }
    }
    const char* Ab = As[tc & 1];
    const char* Bb = Bs[tc & 1];
#pragma unroll
    for (int kf = 0; kf < 2; ++kf) {
      bfrag af[4], bf[2];
#pragma unroll
      for (int mf = 0; mf < 4; ++mf) af[mf] = *(const bfrag*)(Ab + ao[kf][mf]);
#pragma unroll
      for (int nf = 0; nf < 2; ++nf) bf[nf] = *(const bfrag*)(Bb + bo[kf][nf]);
#pragma unroll
      for (int mf = 0; mf < 4; ++mf)
#pragma unroll
        for (int nf = 0; nf < 2; ++nf)
          acc[mf][nf] = __builtin_amdgcn_mfma_f32_16x16x32_bf16(
              af[mf], bf[nf], acc[mf][nf], 0, 0, 0);
    }
    if (tc < 31) {
      char* Aw = As[(tc + 1) & 1];
      char* Bw = Bs[(tc + 1) & 1];
#pragma unroll
      for (int i = 0; i < 4; ++i) {
        uint2 ux; ux.x = cvtpk(xr[i].x, xr[i].y); ux.y = cvtpk(xr[i].z, xr[i].w);
        *(uint2*)(Aw + so[i]) = ux;
        uint2 uw; uw.x = cvtpk(wr[i].x, wr[i].y); uw.y = cvtpk(wr[i].z, wr[i].w);
        *(uint2*)(Bw + so[i]) = uw;
      }
    }
    __syncthreads();
  }

  // epilogue: C/D layout col = lane&15, row = (lane>>4)*4 + j   [m89]
#pragma unroll
  for (int nf = 0; nf < 2; ++nf) {
    int n = wn * 32 + nf * 16 + lr;
    float bias = b1[n] + b2[n];
#pragma unroll
    for (int mf = 0; mf < 4; ++mf) {
      int mr = m0 + wm * 64 + mf * 16 + lq * 4;
#pragma unroll
      for (int j = 0; j < 4; ++j)
        xp1[(size_t)(mr + j) * H + n] = acc[mf][nf][j] + bias;
    }
  }
}

// ---------------------------------------------------------------------------
// Kernel B: fused 2-layer tanh RNN + projection + LayerNorm, f16 dot2 path.
// Weights loaded via inline-asm global_load_dwordx4 (asm volatile results are
// NOT rematerializable -> compiler CANNOT reload them inside the loop; R3-R5
// showed VGPR=52 because plain loads from const-restrict memory were being
// remat'd per step, 24 L2-latency loads on the critical path).
// c-reduction deferred into phase B (linearity of red8): 4 red8/step not 6.
// ---------------------------------------------------------------------------
struct Wrow { unsigned p0, p1, p2, p3, p4, p5, p6, p7; };  // 16 f16 = 8 h2

// non-rematerializable 16B load
__device__ __forceinline__ float4 gload16(const float* p) {
  float4 r;
  asm volatile("global_load_dwordx4 %0, %1, off" : "=v"(r) : "v"(p));
  return r;
}

__device__ __forceinline__ unsigned pkh(float x, float y) {
  h2_t p = {(_Float16)x, (_Float16)y};
  return __builtin_bit_cast(unsigned, p);
}

__device__ __forceinline__ Wrow packrow(float4 a, float4 b, float4 c,
                                        float4 d) {
  Wrow w = {pkh(a.x, a.y), pkh(a.z, a.w), pkh(b.x, b.y), pkh(b.z, b.w),
            pkh(c.x, c.y), pkh(c.z, c.w), pkh(d.x, d.y), pkh(d.z, d.w)};
  return w;
}

__device__ __forceinline__ float d2(unsigned w, int h, float acc) {
  return __builtin_amdgcn_fdot2(__builtin_bit_cast(h2_t, w),
                                __builtin_bit_cast(h2_t, (unsigned)h), acc,
                                false);
}

__device__ __forceinline__ float dot16(Wrow w, int4 lo, int4 hi, float acc) {
  acc = d2(w.p0, lo.x, acc);
  acc = d2(w.p1, lo.y, acc);
  acc = d2(w.p2, lo.z, acc);
  acc = d2(w.p3, lo.w, acc);
  acc = d2(w.p4, hi.x, acc);
  acc = d2(w.p5, hi.y, acc);
  acc = d2(w.p6, hi.z, acc);
  acc = d2(w.p7, hi.w, acc);
  return acc;
}

template <int CTRL>
__device__ __forceinline__ float dpp_add(float x) {
  return x + __builtin_bit_cast(
                 float, __builtin_amdgcn_mov_dpp(__builtin_bit_cast(int, x),
                                                 CTRL, 0xf, 0xf, true));
}

__device__ __forceinline__ float red8(float v) {
  v = dpp_add<0xB1>(v);    // quad_perm [1,0,3,2]  (+ lane^1)
  v = dpp_add<0x4E>(v);    // quad_perm [2,3,0,1]  (+ lane^2)
  v = dpp_add<0x141>(v);   // row_half_mirror      (+ other quad of 8-group)
  return v;
}

__device__ __forceinline__ float fast_tanh(float x) {
  float e = __expf(2.0f * x);
  return 1.0f - 2.0f / (e + 1.0f);
}

__global__ __launch_bounds__(512)
__attribute__((amdgpu_waves_per_eu(1, 2)))
void rnn_fused(
    const float* __restrict__ xp1,
    const float* __restrict__ W_hh1, const float* __restrict__ W_ih2,
    const float* __restrict__ W_hh2, const float* __restrict__ b_ih2,
    const float* __restrict__ b_hh2, const float* __restrict__ W_proj,
    const float* __restrict__ b_proj, const float* __restrict__ gamma,
    const float* __restrict__ beta, float* __restrict__ out) {
  __shared__ __align__(16) _Float16 h1s[2][H];
  __shared__ __align__(16) _Float16 h2s[2][H];
  const int t = threadIdx.x;
  const int b = blockIdx.x;
  const int l = t & 63;
  const int w = t >> 6;
  const int g = (l >> 3) & 7;
  const int q = l & 7;
  const int r0 = 16 * w + g;
  const int r1 = r0 + 8;

  // --- weight loads: inline-asm, non-rematerializable ----------------------
  const float* pA = &W_hh1[r0 * H + 16 * q];
  const float* pB = &W_hh1[r1 * H + 16 * q];
  const float* pC = &W_ih2[r0 * H + 16 * q];
  const float* pD = &W_ih2[r1 * H + 16 * q];
  const float* pE = &W_hh2[r0 * H + 16 * q];
  const float* pF = &W_hh2[r1 * H + 16 * q];
  float4 A0 = gload16(pA), A1 = gload16(pA + 4), A2 = gload16(pA + 8), A3 = gload16(pA + 12);
  float4 B0 = gload16(pB), B1 = gload16(pB + 4), B2 = gload16(pB + 8), B3 = gload16(pB + 12);
  float4 C0 = gload16(pC), C1 = gload16(pC + 4), C2 = gload16(pC + 8), C3 = gload16(pC + 12);
  float4 D0 = gload16(pD), D1 = gload16(pD + 4), D2 = gload16(pD + 8), D3 = gload16(pD + 12);
  float4 E0 = gload16(pE), E1 = gload16(pE + 4), E2 = gload16(pE + 8), E3 = gload16(pE + 12);
  float4 F0 = gload16(pF), F1 = gload16(pF + 4), F2 = gload16(pF + 8), F3 = gload16(pF + 12);
  asm volatile("s_waitcnt vmcnt(0)" ::: "memory");

  Wrow W1r0 = packrow(A0, A1, A2, A3);
  Wrow W1r1 = packrow(B0, B1, B2, B3);
  Wrow W2r0 = packrow(C0, C1, C2, C3);
  Wrow W2r1 = packrow(D0, D1, D2, D3);
  Wrow W3r0 = packrow(E0, E1, E2, E3);
  Wrow W3r1 = packrow(F0, F1, F2, F3);

  const float bias2_0 = b_ih2[r0] + b_hh2[r0];
  const float bias2_1 = b_ih2[r1] + b_hh2[r1];

  if (t < H) { h1s[0][t] = (_Float16)0.f; h2s[0][t] = (_Float16)0.f; }
  __syncthreads();

  const float* xpr0 = xp1 + (size_t)b * T_STEPS * H + r0;
  const float* xpr1 = xpr0 + 8;
  float xpA0 = xpr0[0];
  float xpA1 = xpr1[0];

  for (int ts = 0; ts < T_STEPS; ++ts) {
    const int cur = ts & 1;
    const _Float16* h1p = h1s[cur];
    const _Float16* h2p = h2s[cur];
    _Float16* h1w = h1s[cur ^ 1];
    _Float16* h2w = h2s[cur ^ 1];

    float nx0 = 0.f, nx1 = 0.f;
    if (ts + 1 < T_STEPS) {              // prefetch next step's xp values
      nx0 = xpr0[(size_t)(ts + 1) * H];
      nx1 = xpr1[(size_t)(ts + 1) * H];
    }

    // phase A: a = W_hh1 . h1_old (reduced); c = W_hh2 . h2_old (partial only,
    // reduction deferred into phase B by linearity)
    int4 l1 = *(const int4*)&h1p[16 * q];
    int4 u1 = *(const int4*)&h1p[16 * q + 8];
    int4 l2 = *(const int4*)&h2p[16 * q];
    int4 u2 = *(const int4*)&h2p[16 * q + 8];
    float a0 = dot16(W1r0, l1, u1, 0.f);
    float a1 = dot16(W1r1, l1, u1, 0.f);
    float c0 = dot16(W3r0, l2, u2, 0.f);
    float c1 = dot16(W3r1, l2, u2, 0.f);
    a0 = red8(a0); a1 = red8(a1);
    float h1n0 = fast_tanh(xpA0 + a0);
    float h1n1 = fast_tanh(xpA1 + a1);
    if (q == 0) { h1w[r0] = (_Float16)h1n0; h1w[r1] = (_Float16)h1n1; }
    __syncthreads();  // (1) h1_new visible; reads of old buffers done

    // phase B: W_ih2 . h1_new + c (single combined reduction)
    int4 nl = *(const int4*)&h1w[16 * q];
    int4 nu = *(const int4*)&h1w[16 * q + 8];
    float bb0 = dot16(W2r0, nl, nu, c0);
    float bb1 = dot16(W2r1, nl, nu, c1);
    bb0 = red8(bb0); bb1 = red8(bb1);
    float h2n0 = fast_tanh(bias2_0 + bb0);
    float h2n1 = fast_tanh(bias2_1 + bb1);
    if (q == 0) { h2w[r0] = (_Float16)h2n0; h2w[r1] = (_Float16)h2n1; }
    __syncthreads();  // (2) h2_new visible for next step
    xpA0 = nx0; xpA1 = nx1;
  }
  // T_STEPS even -> final h2 lives in h2s[0]

  // projection + LayerNorm; lanes 0..63 == wave 0 exactly
  if (t < PROJ) {
    const float* wp = W_proj + t * H;
    float z = b_proj[t];
#pragma unroll
    for (int i = 0; i < 32; ++i) {
      float4 wv = *(const float4*)&wp[4 * i];
      z = fmaf(wv.x, (float)h2s[0][4 * i + 0], z);
      z = fmaf(wv.y, (float)h2s[0][4 * i + 1], z);
      z = fmaf(wv.z, (float)h2s[0][4 * i + 2], z);
      z = fmaf(wv.w, (float)h2s[0][4 * i + 3], z);
    }
    float s = z;
#pragma unroll
    for (int d = 1; d < 64; d <<= 1) s += __shfl_xor(s, d);
    float mu = s * 0.015625f;
    float dz = z - mu;
    float v = dz * dz;
#pragma unroll
    for (int d = 1; d < 64; d <<= 1) v += __shfl_xor(v, d);
    float rstd = rsqrtf(v * 0.015625f + 1e-5f);
    out[b * PROJ + t] = dz * rstd * gamma[t] + beta[t];
  }
}

extern "C" void kernel_launch(void* const* d_in, const int* in_sizes, int n_in,
                              void* d_out, int out_size, void* d_ws, size_t ws_size,
                              hipStream_t stream) {
  const float* x      = (const float*)d_in[0];
  const float* W_ih1  = (const float*)d_in[1];
  const float* W_hh1  = (const float*)d_in[2];
  const float* b_ih1  = (const float*)d_in[3];
  const float* b_hh1  = (const float*)d_in[4];
  const float* W_ih2  = (const float*)d_in[5];
  const float* W_hh2  = (const float*)d_in[6];
  const float* b_ih2  = (const float*)d_in[7];
  const float* b_hh2  = (const float*)d_in[8];
  const float* W_proj = (const float*)d_in[9];
  const float* b_proj = (const float*)d_in[10];
  const float* gamma  = (const float*)d_in[11];
  const float* beta   = (const float*)d_in[12];

  float* xp1 = (float*)d_ws;   // BT*H*4 = 16 MB scratch

  xp1_gemm<<<BT / BM, 512, 0, stream>>>(x, W_ih1, b_ih1, b_hh1, xp1);
  rnn_fused<<<BATCH, 512, 0, stream>>>(xp1, W_hh1, W_ih2, W_hh2, b_ih2, b_hh2,
                                       W_proj, b_proj, gamma, beta,
                                       (float*)d_out);
}

// Round 7
// 409.921 us; speedup vs baseline: 1.1877x; 1.0509x over previous
//
#include <hip/hip_runtime.h>
#include <math.h>

#define H 128
#define IN 2048
#define PROJ 64
#define BT 32768      // B*T rows of x
#define T_STEPS 512
#define BATCH 64
#define BM 128
#define BKA 64

using f32x4  = __attribute__((ext_vector_type(4))) float;
using bfrag  = __attribute__((ext_vector_type(8))) short;   // 8 bf16
using h2_t   = __attribute__((ext_vector_type(2))) _Float16;

// v_cvt_pk_bf16_f32: d.lo = bf16(lo), d.hi = bf16(hi)  (RNE)
__device__ __forceinline__ unsigned cvtpk(float lo, float hi) {
  unsigned r;
  asm("v_cvt_pk_bf16_f32 %0, %1, %2" : "=v"(r) : "v"(lo), "v"(hi));
  return r;
}

// ---------------------------------------------------------------------------
// Kernel A: xp1[BT][H] = x[BT][IN] @ W_ih1^T + (b_ih1+b_hh1), bf16 MFMA.
// 256 blocks x 512 thr (8 waves, 2Mx4N). Tile 128(M) x 128(N=H) x 64(K).
// Reg-staged 1-deep pipeline, one barrier per chunk, XOR-swizzled LDS.
// ~60 us, near the 268 MB / 6.3 TB/s HBM floor. UNCHANGED.
// ---------------------------------------------------------------------------
__global__ __launch_bounds__(512) void xp1_gemm(
    const float* __restrict__ x, const float* __restrict__ W,
    const float* __restrict__ b1, const float* __restrict__ b2,
    float* __restrict__ xp1) {
  __shared__ __align__(16) char As[2][BM * BKA * 2];   // 2 x 16 KB
  __shared__ __align__(16) char Bs[2][H * BKA * 2];    // 2 x 16 KB
  const int t  = threadIdx.x;
  const int m0 = blockIdx.x * BM;
  const int wv = t >> 6, l = t & 63;
  const int wm = wv >> 2;
  const int wn = wv & 3;
  const int lr = l & 15;
  const int lq = l >> 4;

  const float* xg[4];
  const float* wg[4];
  int so[4];
#pragma unroll
  for (int i = 0; i < 4; ++i) {
    int c = t + 512 * i, r = c >> 4, k4 = c & 15;
    xg[i] = x + (size_t)(m0 + r) * IN + k4 * 4;
    wg[i] = W + (size_t)r * IN + k4 * 4;
    so[i] = (r * 128 + k4 * 8) ^ ((r & 7) << 4);
  }
  int ao[2][4], bo[2][2];
#pragma unroll
  for (int kf = 0; kf < 2; ++kf) {
#pragma unroll
    for (int mf = 0; mf < 4; ++mf) {
      int r = wm * 64 + mf * 16 + lr;
      ao[kf][mf] = (r * 128 + kf * 64 + lq * 16) ^ ((r & 7) << 4);
    }
#pragma unroll
    for (int nf = 0; nf < 2; ++nf) {
      int r = wn * 32 + nf * 16 + lr;
      bo[kf][nf] = (r * 128 + kf * 64 + lq * 16) ^ ((r & 7) << 4);
    }
  }

  f32x4 acc[4][2];
#pragma unroll
  for (int mf = 0; mf < 4; ++mf)
#pragma unroll
    for (int nf = 0; nf < 2; ++nf)
#pragma unroll
      for (int j = 0; j < 4; ++j) acc[mf][nf][j] = 0.f;

  float4 xr[4], wr[4];
#pragma unroll
  for (int i = 0; i < 4; ++i) {
    xr[i] = *(const float4*)&xg[i][0];
    wr[i] = *(const float4*)&wg[i][0];
  }
#pragma unroll
  for (int i = 0; i < 4; ++i) {
    uint2 ux; ux.x = cvtpk(xr[i].x, xr[i].y); ux.y = cvtpk(xr[i].z, xr[i].w);
    *(uint2*)(As[0] + so[i]) = ux;
    uint2 uw; uw.x = cvtpk(wr[i].x, wr[i].y); uw.y = cvtpk(wr[i].z, wr[i].w);
    *(uint2*)(Bs[0] + so[i]) = uw;
  }
  __syncthreads();

  for (int tc = 0; tc < 32; ++tc) {
    const int kc = (tc + 1) * BKA;
    if (tc < 31) {
#pragma unroll
      for (int i = 0; i < 4; ++i) {
        xr[i] = *(const float4*)&xg[i][kc];
        wr[i] = *(const float4*)&wg[i][kc];
      }
    }
    const char* Ab = As[tc & 1];
    const char* Bb = Bs[tc & 1];
#pragma unroll
    for (int kf = 0; kf < 2; ++kf) {
      bfrag af[4], bf[2];
#pragma unroll
      for (int mf = 0; mf < 4; ++mf) af[mf] = *(const bfrag*)(Ab + ao[kf][mf]);
#pragma unroll
      for (int nf = 0; nf < 2; ++nf) bf[nf] = *(const bfrag*)(Bb + bo[kf][nf]);
#pragma unroll
      for (int mf = 0; mf < 4; ++mf)
#pragma unroll
        for (int nf = 0; nf < 2; ++nf)
          acc[mf][nf] = __builtin_amdgcn_mfma_f32_16x16x32_bf16(
              af[mf], bf[nf], acc[mf][nf], 0, 0, 0);
    }
    if (tc < 31) {
      char* Aw = As[(tc + 1) & 1];
      char* Bw = Bs[(tc + 1) & 1];
#pragma unroll
      for (int i = 0; i < 4; ++i) {
        uint2 ux; ux.x = cvtpk(xr[i].x, xr[i].y); ux.y = cvtpk(xr[i].z, xr[i].w);
        *(uint2*)(Aw + so[i]) = ux;
        uint2 uw; uw.x = cvtpk(wr[i].x, wr[i].y); uw.y = cvtpk(wr[i].z, wr[i].w);
        *(uint2*)(Bw + so[i]) = uw;
      }
    }
    __syncthreads();
  }

  // epilogue: C/D layout col = lane&15, row = (lane>>4)*4 + j   [m89]
#pragma unroll
  for (int nf = 0; nf < 2; ++nf) {
    int n = wn * 32 + nf * 16 + lr;
    float bias = b1[n] + b2[n];
#pragma unroll
    for (int mf = 0; mf < 4; ++mf) {
      int mr = m0 + wm * 64 + mf * 16 + lq * 4;
#pragma unroll
      for (int j = 0; j < 4; ++j)
        xp1[(size_t)(mr + j) * H + n] = acc[mf][nf][j] + bias;
    }
  }
}

// ---------------------------------------------------------------------------
// Kernel B: fused 2-layer tanh RNN, SKEWED pipeline: at iteration i compute
// h1[i] (needs h1[i-1]) AND h2[i-1] (needs h1[i-1], h2[i-2]) -> all operands
// predate the last barrier -> ONE barrier & ONE phase per step (was 2).
// h1[i-1] read once, feeds both W_hh1 and W_ih2 dots: 4 ds_read_b128/iter.
// Weights via non-remat inline-asm loads (R6: VGPR 52->64, resident).
// Buffers: read h1s[(i-1)&1], h2s[i&1]; write h1s[i&1], h2s[(i-1)&1].
// Final h2 lands in h2s[1] (T even). Peel i=0 (h1 only), i=T (h2 only).
// ---------------------------------------------------------------------------
struct Wrow { unsigned p0, p1, p2, p3, p4, p5, p6, p7; };  // 16 f16 = 8 h2

// non-rematerializable 16B load
__device__ __forceinline__ float4 gload16(const float* p) {
  float4 r;
  asm volatile("global_load_dwordx4 %0, %1, off" : "=v"(r) : "v"(p));
  return r;
}

__device__ __forceinline__ unsigned pkh(float x, float y) {
  h2_t p = {(_Float16)x, (_Float16)y};
  return __builtin_bit_cast(unsigned, p);
}

__device__ __forceinline__ Wrow packrow(float4 a, float4 b, float4 c,
                                        float4 d) {
  Wrow w = {pkh(a.x, a.y), pkh(a.z, a.w), pkh(b.x, b.y), pkh(b.z, b.w),
            pkh(c.x, c.y), pkh(c.z, c.w), pkh(d.x, d.y), pkh(d.z, d.w)};
  return w;
}

__device__ __forceinline__ float d2(unsigned w, int h, float acc) {
  return __builtin_amdgcn_fdot2(__builtin_bit_cast(h2_t, w),
                                __builtin_bit_cast(h2_t, (unsigned)h), acc,
                                false);
}

__device__ __forceinline__ float dot16(Wrow w, int4 lo, int4 hi, float acc) {
  acc = d2(w.p0, lo.x, acc);
  acc = d2(w.p1, lo.y, acc);
  acc = d2(w.p2, lo.z, acc);
  acc = d2(w.p3, lo.w, acc);
  acc = d2(w.p4, hi.x, acc);
  acc = d2(w.p5, hi.y, acc);
  acc = d2(w.p6, hi.z, acc);
  acc = d2(w.p7, hi.w, acc);
  return acc;
}

template <int CTRL>
__device__ __forceinline__ float dpp_add(float x) {
  return x + __builtin_bit_cast(
                 float, __builtin_amdgcn_mov_dpp(__builtin_bit_cast(int, x),
                                                 CTRL, 0xf, 0xf, true));
}

__device__ __forceinline__ float red8(float v) {
  v = dpp_add<0xB1>(v);    // quad_perm [1,0,3,2]  (+ lane^1)
  v = dpp_add<0x4E>(v);    // quad_perm [2,3,0,1]  (+ lane^2)
  v = dpp_add<0x141>(v);   // row_half_mirror      (+ other quad of 8-group)
  return v;
}

__device__ __forceinline__ float fast_tanh(float x) {
  float e = __expf(2.0f * x);
  return 1.0f - 2.0f / (e + 1.0f);
}

__global__ __launch_bounds__(512)
__attribute__((amdgpu_waves_per_eu(1, 2)))
void rnn_fused(
    const float* __restrict__ xp1,
    const float* __restrict__ W_hh1, const float* __restrict__ W_ih2,
    const float* __restrict__ W_hh2, const float* __restrict__ b_ih2,
    const float* __restrict__ b_hh2, const float* __restrict__ W_proj,
    const float* __restrict__ b_proj, const float* __restrict__ gamma,
    const float* __restrict__ beta, float* __restrict__ out) {
  __shared__ __align__(16) _Float16 h1s[2][H];
  __shared__ __align__(16) _Float16 h2s[2][H];
  const int t = threadIdx.x;
  const int b = blockIdx.x;
  const int l = t & 63;
  const int w = t >> 6;
  const int g = (l >> 3) & 7;
  const int q = l & 7;
  const int r0 = 16 * w + g;
  const int r1 = r0 + 8;

  // --- weight loads: inline-asm, non-rematerializable ----------------------
  const float* pA = &W_hh1[r0 * H + 16 * q];
  const float* pB = &W_hh1[r1 * H + 16 * q];
  const float* pC = &W_ih2[r0 * H + 16 * q];
  const float* pD = &W_ih2[r1 * H + 16 * q];
  const float* pE = &W_hh2[r0 * H + 16 * q];
  const float* pF = &W_hh2[r1 * H + 16 * q];
  float4 A0 = gload16(pA), A1 = gload16(pA + 4), A2 = gload16(pA + 8), A3 = gload16(pA + 12);
  float4 B0 = gload16(pB), B1 = gload16(pB + 4), B2 = gload16(pB + 8), B3 = gload16(pB + 12);
  float4 C0 = gload16(pC), C1 = gload16(pC + 4), C2 = gload16(pC + 8), C3 = gload16(pC + 12);
  float4 D0 = gload16(pD), D1 = gload16(pD + 4), D2 = gload16(pD + 8), D3 = gload16(pD + 12);
  float4 E0 = gload16(pE), E1 = gload16(pE + 4), E2 = gload16(pE + 8), E3 = gload16(pE + 12);
  float4 F0 = gload16(pF), F1 = gload16(pF + 4), F2 = gload16(pF + 8), F3 = gload16(pF + 12);
  asm volatile("s_waitcnt vmcnt(0)" ::: "memory");

  Wrow W1r0 = packrow(A0, A1, A2, A3);
  Wrow W1r1 = packrow(B0, B1, B2, B3);
  Wrow W2r0 = packrow(C0, C1, C2, C3);
  Wrow W2r1 = packrow(D0, D1, D2, D3);
  Wrow W3r0 = packrow(E0, E1, E2, E3);
  Wrow W3r1 = packrow(F0, F1, F2, F3);

  const float bias2_0 = b_ih2[r0] + b_hh2[r0];
  const float bias2_1 = b_ih2[r1] + b_hh2[r1];

  // h1[-1], h2[-1] live in buffer parity (-1)&1 == 1
  if (t < H) { h1s[1][t] = (_Float16)0.f; h2s[1][t] = (_Float16)0.f; }
  __syncthreads();

  const float* xpr0 = xp1 + (size_t)b * T_STEPS * H + r0;
  const float* xpr1 = xpr0 + 8;

  // peel i = 0: h1[0] = tanh(xp[0] + W_hh1 . 0) = tanh(xp[0]); no h2 yet
  if (q == 0) {
    h1s[0][r0] = (_Float16)fast_tanh(xpr0[0]);
    h1s[0][r1] = (_Float16)fast_tanh(xpr1[0]);
  }
  __syncthreads();

  float xpc0 = xpr0[H];   // xp[1]
  float xpc1 = xpr1[H];

  for (int i = 1; i < T_STEPS; ++i) {
    const _Float16* h1p = h1s[(i - 1) & 1];   // h1[i-1]
    const _Float16* h2p = h2s[i & 1];         // h2[i-2]
    _Float16* h1w = h1s[i & 1];               // h1[i]
    _Float16* h2w = h2s[(i - 1) & 1];         // h2[i-1]

    float nx0 = 0.f, nx1 = 0.f;
    if (i + 1 < T_STEPS) {                    // prefetch xp[i+1]
      nx0 = xpr0[(size_t)(i + 1) * H];
      nx1 = xpr1[(size_t)(i + 1) * H];
    }

    int4 l1 = *(const int4*)&h1p[16 * q];     // h1[i-1] (used twice)
    int4 u1 = *(const int4*)&h1p[16 * q + 8];
    int4 l2 = *(const int4*)&h2p[16 * q];     // h2[i-2]
    int4 u2 = *(const int4*)&h2p[16 * q + 8];

    float a0 = dot16(W1r0, l1, u1, 0.f);      // W_hh1 . h1[i-1]
    float a1 = dot16(W1r1, l1, u1, 0.f);
    float c0 = dot16(W3r0, l2, u2, 0.f);      // W_hh2 . h2[i-2] (partial)
    float c1 = dot16(W3r1, l2, u2, 0.f);
    float bb0 = dot16(W2r0, l1, u1, c0);      // W_ih2 . h1[i-1] + c
    float bb1 = dot16(W2r1, l1, u1, c1);

    a0 = red8(a0); a1 = red8(a1);
    bb0 = red8(bb0); bb1 = red8(bb1);

    float h1n0 = fast_tanh(xpc0 + a0);        // h1[i]
    float h1n1 = fast_tanh(xpc1 + a1);
    float h2n0 = fast_tanh(bias2_0 + bb0);    // h2[i-1]
    float h2n1 = fast_tanh(bias2_1 + bb1);
    if (q == 0) {
      h1w[r0] = (_Float16)h1n0; h1w[r1] = (_Float16)h1n1;
      h2w[r0] = (_Float16)h2n0; h2w[r1] = (_Float16)h2n1;
    }
    __syncthreads();                          // the ONLY barrier per step
    xpc0 = nx0; xpc1 = nx1;
  }

  // peel i = T_STEPS: h2[T-1] = tanh(bias2 + W_ih2.h1[T-1] + W_hh2.h2[T-2])
  {
    const _Float16* h1p = h1s[(T_STEPS - 1) & 1];   // h1s[1]: h1[T-1]
    const _Float16* h2p = h2s[T_STEPS & 1];         // h2s[0]: h2[T-2]
    _Float16* h2w = h2s[(T_STEPS - 1) & 1];         // h2s[1]: h2[T-1]
    int4 l1 = *(const int4*)&h1p[16 * q];
    int4 u1 = *(const int4*)&h1p[16 * q + 8];
    int4 l2 = *(const int4*)&h2p[16 * q];
    int4 u2 = *(const int4*)&h2p[16 * q + 8];
    float c0 = dot16(W3r0, l2, u2, 0.f);
    float c1 = dot16(W3r1, l2, u2, 0.f);
    float bb0 = dot16(W2r0, l1, u1, c0);
    float bb1 = dot16(W2r1, l1, u1, c1);
    bb0 = red8(bb0); bb1 = red8(bb1);
    if (q == 0) {
      h2w[r0] = (_Float16)fast_tanh(bias2_0 + bb0);
      h2w[r1] = (_Float16)fast_tanh(bias2_1 + bb1);
    }
    __syncthreads();
  }

  // projection + LayerNorm on h2s[1]; lanes 0..63 == wave 0 exactly
  if (t < PROJ) {
    const float* wp = W_proj + t * H;
    float z = b_proj[t];
#pragma unroll
    for (int i = 0; i < 32; ++i) {
      float4 wv = *(const float4*)&wp[4 * i];
      z = fmaf(wv.x, (float)h2s[1][4 * i + 0], z);
      z = fmaf(wv.y, (float)h2s[1][4 * i + 1], z);
      z = fmaf(wv.z, (float)h2s[1][4 * i + 2], z);
      z = fmaf(wv.w, (float)h2s[1][4 * i + 3], z);
    }
    float s = z;
#pragma unroll
    for (int d = 1; d < 64; d <<= 1) s += __shfl_xor(s, d);
    float mu = s * 0.015625f;
    float dz = z - mu;
    float v = dz * dz;
#pragma unroll
    for (int d = 1; d < 64; d <<= 1) v += __shfl_xor(v, d);
    float rstd = rsqrtf(v * 0.015625f + 1e-5f);
    out[b * PROJ + t] = dz * rstd * gamma[t] + beta[t];
  }
}

extern "C" void kernel_launch(void* const* d_in, const int* in_sizes, int n_in,
                              void* d_out, int out_size, void* d_ws, size_t ws_size,
                              hipStream_t stream) {
  const float* x      = (const float*)d_in[0];
  const float* W_ih1  = (const float*)d_in[1];
  const float* W_hh1  = (const float*)d_in[2];
  const float* b_ih1  = (const float*)d_in[3];
  const float* b_hh1  = (const float*)d_in[4];
  const float* W_ih2  = (const float*)d_in[5];
  const float* W_hh2  = (const float*)d_in[6];
  const float* b_ih2  = (const float*)d_in[7];
  const float* b_hh2  = (const float*)d_in[8];
  const float* W_proj = (const float*)d_in[9];
  const float* b_proj = (const float*)d_in[10];
  const float* gamma  = (const float*)d_in[11];
  const float* beta   = (const float*)d_in[12];

  float* xp1 = (float*)d_ws;   // BT*H*4 = 16 MB scratch

  xp1_gemm<<<BT / BM, 512, 0, stream>>>(x, W_ih1, b_ih1, b_hh1, xp1);
  rnn_fused<<<BATCH, 512, 0, stream>>>(xp1, W_hh1, W_ih2, W_hh2, b_ih2, b_hh2,
                                       W_proj, b_proj, gamma, beta,
                                       (float*)d_out);
}